// Round 4
// baseline (496.676 us; speedup 1.0000x reference)
//
#include <hip/hip_runtime.h>
#include <hip/hip_bf16.h>

#define D 128
#define EPB 32   // edges per block (MFMA kernels)
#define NB 256   // blocks for hist/write passes

typedef __attribute__((ext_vector_type(8))) short bf16x8;
typedef __attribute__((ext_vector_type(4))) float f32x4;

__device__ inline unsigned short f2bf(float f) {
    union { float f; unsigned int u; } v;
    v.f = f;
    unsigned int u = v.u;
    unsigned int r = u + 0x7fffu + ((u >> 16) & 1u);  // RNE
    return (unsigned short)(r >> 16);
}
__device__ inline float bf2f(unsigned short b) {
    union { unsigned int u; float f; } v;
    v.u = ((unsigned int)b) << 16;
    return v.f;
}

// ---------------- out = x (round-3 fallback only) ----------------
__global__ __launch_bounds__(256) void copy_kernel(float* __restrict__ out,
                                                   const float* __restrict__ x,
                                                   int n_elems) {
    int n4 = n_elems >> 2;
    const float4* src = (const float4*)x;
    float4* dst = (float4*)out;
    for (int i = blockIdx.x * blockDim.x + threadIdx.x; i < n4;
         i += gridDim.x * blockDim.x)
        dst[i] = src[i];
}

// ---------------- W[t][k][c] fp32 -> Wt[t][c][k] bf16 ----------------
__global__ __launch_bounds__(256) void conv_w(const float* __restrict__ W,
                                              unsigned short* __restrict__ Wt,
                                              int K) {
    __shared__ float tile[32][33];
    int k0 = blockIdx.x * 32, c0 = blockIdx.y * 32, t = blockIdx.z;
    int tr = threadIdx.x >> 5, tc = threadIdx.x & 31;
#pragma unroll
    for (int m = 0; m < 4; m++)
        tile[m * 8 + tr][tc] = W[((size_t)t * K + k0 + m * 8 + tr) * D + c0 + tc];
    __syncthreads();
#pragma unroll
    for (int m = 0; m < 4; m++)
        Wt[((size_t)t * D + c0 + m * 8 + tr) * K + k0 + tc] = f2bf(tile[tc][m * 8 + tr]);
}

// ---------------- type-sort pass 1: per-block histogram ----------------
__global__ __launch_bounds__(256) void hist_types(const int* __restrict__ type,
                                                  int n, int* __restrict__ hist) {
    __shared__ int h[4];
    if (threadIdx.x < 4) h[threadIdx.x] = 0;
    __syncthreads();
    for (int i = blockIdx.x * 256 + threadIdx.x; i < n; i += NB * 256)
        atomicAdd(&h[type[i]], 1);
    __syncthreads();
    if (threadIdx.x < 4) hist[blockIdx.x * 4 + threadIdx.x] = h[threadIdx.x];
}

// meta: [0..3]=total1, [4..7]=total2, [8..12]=pb1, [13..17]=pb2
__global__ void scan_offsets(int* __restrict__ meta,
                             const int* __restrict__ hist1, int* __restrict__ off1,
                             const int* __restrict__ hist2, int* __restrict__ off2) {
    int t = threadIdx.x;
    if (t < 4) {
        int s = 0;
        for (int b = 0; b < NB; b++) s += hist1[b * 4 + t];
        meta[t] = s;
    } else if (t < 8) {
        int tt = t - 4, s = 0;
        for (int b = 0; b < NB; b++) s += hist2[b * 4 + tt];
        meta[4 + tt] = s;
    }
    __syncthreads();
    if (t == 0) {
        int p = 0;
        for (int k = 0; k < 4; k++) {
            meta[8 + k] = p;
            p += ((meta[k] + EPB - 1) / EPB) * EPB;
        }
        meta[12] = p;
        p = 0;
        for (int k = 0; k < 4; k++) {
            meta[13 + k] = p;
            p += ((meta[4 + k] + EPB - 1) / EPB) * EPB;
        }
        meta[17] = p;
    }
    __syncthreads();
    if (t < 4) {
        int p = meta[8 + t];
        for (int b = 0; b < NB; b++) { off1[b * 4 + t] = p; p += hist1[b * 4 + t]; }
    } else if (t < 8) {
        int tt = t - 4;
        int p = meta[13 + tt];
        for (int b = 0; b < NB; b++) { off2[b * 4 + tt] = p; p += hist2[b * 4 + tt]; }
    }
}

__global__ __launch_bounds__(256) void write_sorted(const int* __restrict__ type,
                                                    int n,
                                                    const int* __restrict__ off,
                                                    int* __restrict__ sorted) {
    __shared__ int loff[4];
    if (threadIdx.x < 4) loff[threadIdx.x] = off[blockIdx.x * 4 + threadIdx.x];
    __syncthreads();
    for (int i = blockIdx.x * 256 + threadIdx.x; i < n; i += NB * 256) {
        int t = type[i];
        int pos = atomicAdd(&loff[t], 1);
        sorted[pos] = i;
    }
}

// ---------------- tgt machinery: slot assignment + scan ----------------
__global__ __launch_bounds__(256) void assign_rel(const int* __restrict__ tgt, int n,
                                                  int* __restrict__ cnt,
                                                  int* __restrict__ pos) {
    for (int i = blockIdx.x * blockDim.x + threadIdx.x; i < n;
         i += gridDim.x * blockDim.x)
        pos[i] = atomicAdd(&cnt[tgt[i]], 1);
}

__global__ __launch_bounds__(1024) void scan_count(const int* __restrict__ cnt, int n,
                                                   int* __restrict__ base) {
    __shared__ int part[1024];
    int t = threadIdx.x;
    int chunk = (n + 1023) >> 10;
    int lo = min(t * chunk, n), hi = min(lo + chunk, n);
    int s = 0;
    for (int i = lo; i < hi; i++) s += cnt[i];
    part[t] = s;
    __syncthreads();
    for (int off = 1; off < 1024; off <<= 1) {
        int v = part[t];
        if (t >= off) v += part[t - off];
        __syncthreads();
        part[t] = v;
        __syncthreads();
    }
    int run = (t > 0) ? part[t - 1] : 0;
    for (int i = lo; i < hi; i++) { base[i] = run; run += cnt[i]; }
    if (lo < n && hi == n) base[n] = run;
}

// ================= MFMA edge kernels (message-writing) =================
// Block = 32 same-type edges, 4 waves; wave w -> out cols [32w,32w+32).
// C/D: col=lane&15, row=(lane>>4)*4+reg

__global__ __launch_bounds__(256) void edge1_msg(
    const float* __restrict__ x, const unsigned short* __restrict__ Wt1,
    const int* __restrict__ src, const int* __restrict__ tgt,
    const int* __restrict__ sorted, const int* __restrict__ meta,
    const int* __restrict__ basep, const int* __restrict__ pos,
    unsigned short* __restrict__ msg) {
    __shared__ uint4 As4[512];
    __shared__ int s_mrow[EPB];
    __shared__ int s_src[EPB];
    char* As = (char*)As4;

    int tid = threadIdx.x;
    int g0 = blockIdx.x * EPB;
    const int* pb = meta + 8;
    int t = 0;
#pragma unroll
    for (int k = 1; k < 4; k++)
        if (g0 >= pb[k]) t = k;
    const unsigned short* __restrict__ W = Wt1 + (size_t)t * D * D;

    if (tid < EPB) {
        int eid = sorted[g0 + tid];
        int sv = -1, mr = -1;
        if (eid >= 0) { sv = src[eid]; mr = basep[tgt[eid]] + pos[eid]; }
        s_src[tid] = sv;
        s_mrow[tid] = mr;
    }
    __syncthreads();

    {
        int r = tid >> 3, u0 = tid & 7;
        int sv = s_src[r];
        const float4* srow = (const float4*)(x + (size_t)sv * D);
#pragma unroll
        for (int q = 0; q < 4; q++) {
            int u = u0 + 8 * q;
            float4 v = make_float4(0.f, 0.f, 0.f, 0.f);
            if (sv >= 0) v = srow[u];
            uint2 p;
            p.x = (unsigned)f2bf(v.x) | ((unsigned)f2bf(v.y) << 16);
            p.y = (unsigned)f2bf(v.z) | ((unsigned)f2bf(v.w) << 16);
            int byte = ((((u >> 1) * 16) ^ ((r & 7) << 4)) + (u & 1) * 8);
            *(uint2*)(As + r * 256 + byte) = p;
        }
    }
    __syncthreads();

    int wave = tid >> 6, lane = tid & 63;
    int c0 = wave * 32;
    int lrow = lane & 15, lgrp = lane >> 4;

    bf16x8 b[2][4];
#pragma unroll
    for (int fc = 0; fc < 2; fc++)
#pragma unroll
        for (int kk = 0; kk < 4; kk++)
            b[fc][kk] = *(const bf16x8*)(W + (size_t)(c0 + fc * 16 + lrow) * D +
                                         kk * 32 + lgrp * 8);

    f32x4 acc[2][2];
#pragma unroll
    for (int i = 0; i < 2; i++)
#pragma unroll
        for (int j = 0; j < 2; j++) acc[i][j] = (f32x4){0.f, 0.f, 0.f, 0.f};

#pragma unroll
    for (int kk = 0; kk < 4; kk++) {
        bf16x8 a0, a1;
        {
            int r = lrow;
            a0 = *(const bf16x8*)(As + r * 256 +
                                  ((kk * 64 + lgrp * 16) ^ ((r & 7) << 4)));
        }
        {
            int r = 16 + lrow;
            a1 = *(const bf16x8*)(As + r * 256 +
                                  ((kk * 64 + lgrp * 16) ^ ((r & 7) << 4)));
        }
        acc[0][0] = __builtin_amdgcn_mfma_f32_16x16x32_bf16(a0, b[0][kk], acc[0][0], 0, 0, 0);
        acc[1][0] = __builtin_amdgcn_mfma_f32_16x16x32_bf16(a1, b[0][kk], acc[1][0], 0, 0, 0);
        acc[0][1] = __builtin_amdgcn_mfma_f32_16x16x32_bf16(a0, b[1][kk], acc[0][1], 0, 0, 0);
        acc[1][1] = __builtin_amdgcn_mfma_f32_16x16x32_bf16(a1, b[1][kk], acc[1][1], 0, 0, 0);
    }

#pragma unroll
    for (int fr = 0; fr < 2; fr++)
#pragma unroll
        for (int reg = 0; reg < 4; reg++) {
            int erow = fr * 16 + lgrp * 4 + reg;
            int mr = s_mrow[erow];
            if (mr >= 0) {
#pragma unroll
                for (int fc = 0; fc < 2; fc++)
                    msg[(size_t)mr * D + c0 + fc * 16 + lrow] =
                        f2bf(acc[fr][fc][reg]);
            }
        }
}

__global__ __launch_bounds__(256) void edge2_msg(
    const float* __restrict__ x, const unsigned short* __restrict__ Wt2,
    const int* __restrict__ src2, const int* __restrict__ tgt,
    const int* __restrict__ sorted, const int* __restrict__ meta,
    const int* __restrict__ basep, const int* __restrict__ pos,
    unsigned short* __restrict__ msg) {
    __shared__ uint4 As4[1024];
    __shared__ int s_mrow[EPB];
    __shared__ int s_srcA[EPB];
    __shared__ int s_srcB[EPB];
    char* As = (char*)As4;

    int tid = threadIdx.x;
    int g0 = blockIdx.x * EPB;
    const int* pb = meta + 13;
    int t = 0;
#pragma unroll
    for (int k = 1; k < 4; k++)
        if (g0 >= pb[k]) t = k;
    const unsigned short* __restrict__ W = Wt2 + (size_t)t * D * 2 * D;

    if (tid < EPB) {
        int eid = sorted[g0 + tid];
        int sa = -1, sb = -1, mr = -1;
        if (eid >= 0) {
            sa = src2[2 * eid];
            sb = src2[2 * eid + 1];
            mr = basep[tgt[eid]] + pos[eid];
        }
        s_srcA[tid] = sa;
        s_srcB[tid] = sb;
        s_mrow[tid] = mr;
    }
    __syncthreads();

    {
        int r = tid >> 3, u0 = tid & 7;
        int sa = s_srcA[r], sb = s_srcB[r];
        const float4* rowA = (const float4*)(x + (size_t)sa * D);
        const float4* rowB = (const float4*)(x + (size_t)sb * D);
#pragma unroll
        for (int q = 0; q < 8; q++) {
            int u = u0 + 8 * q;
            float4 v = make_float4(0.f, 0.f, 0.f, 0.f);
            if (sa >= 0) v = (u < 32) ? rowA[u] : rowB[u - 32];
            uint2 p;
            p.x = (unsigned)f2bf(v.x) | ((unsigned)f2bf(v.y) << 16);
            p.y = (unsigned)f2bf(v.z) | ((unsigned)f2bf(v.w) << 16);
            int byte = ((((u >> 1) * 16) ^ ((r & 7) << 4)) + (u & 1) * 8);
            *(uint2*)(As + r * 512 + byte) = p;
        }
    }
    __syncthreads();

    int wave = tid >> 6, lane = tid & 63;
    int c0 = wave * 32;
    int lrow = lane & 15, lgrp = lane >> 4;

    f32x4 acc[2][2];
#pragma unroll
    for (int i = 0; i < 2; i++)
#pragma unroll
        for (int j = 0; j < 2; j++) acc[i][j] = (f32x4){0.f, 0.f, 0.f, 0.f};

#pragma unroll
    for (int kk = 0; kk < 8; kk++) {
        bf16x8 b0 = *(const bf16x8*)(W + (size_t)(c0 + lrow) * 2 * D + kk * 32 + lgrp * 8);
        bf16x8 b1 = *(const bf16x8*)(W + (size_t)(c0 + 16 + lrow) * 2 * D + kk * 32 + lgrp * 8);
        bf16x8 a0, a1;
        {
            int r = lrow;
            a0 = *(const bf16x8*)(As + r * 512 +
                                  ((kk * 64 + lgrp * 16) ^ ((r & 7) << 4)));
        }
        {
            int r = 16 + lrow;
            a1 = *(const bf16x8*)(As + r * 512 +
                                  ((kk * 64 + lgrp * 16) ^ ((r & 7) << 4)));
        }
        acc[0][0] = __builtin_amdgcn_mfma_f32_16x16x32_bf16(a0, b0, acc[0][0], 0, 0, 0);
        acc[1][0] = __builtin_amdgcn_mfma_f32_16x16x32_bf16(a1, b0, acc[1][0], 0, 0, 0);
        acc[0][1] = __builtin_amdgcn_mfma_f32_16x16x32_bf16(a0, b1, acc[0][1], 0, 0, 0);
        acc[1][1] = __builtin_amdgcn_mfma_f32_16x16x32_bf16(a1, b1, acc[1][1], 0, 0, 0);
    }

#pragma unroll
    for (int fr = 0; fr < 2; fr++)
#pragma unroll
        for (int reg = 0; reg < 4; reg++) {
            int erow = fr * 16 + lgrp * 4 + reg;
            int mr = s_mrow[erow];
            if (mr >= 0) {
#pragma unroll
                for (int fc = 0; fc < 2; fc++)
                    msg[(size_t)mr * D + c0 + fc * 16 + lrow] =
                        f2bf(acc[fr][fc][reg]);
            }
        }
}

// ---------------- phase 2: out = x + contiguous segment sum ----------------
__global__ __launch_bounds__(256) void finalize(
    const float* __restrict__ x, const unsigned short* __restrict__ msg,
    const int* __restrict__ basep, float* __restrict__ out, int nn) {
    int wib = threadIdx.x >> 6, lane = threadIdx.x & 63;
    for (int v = blockIdx.x * 4 + wib; v < nn; v += gridDim.x * 4) {
        int b0 = basep[v], b1 = basep[v + 1];
        float2 xv = *(const float2*)(x + (size_t)v * D + lane * 2);
        float a0 = xv.x, a1 = xv.y;
        for (int i = b0; i < b1; i++) {
            unsigned u = *(const unsigned*)(msg + (size_t)i * D + lane * 2);
            a0 += bf2f((unsigned short)(u & 0xffff));
            a1 += bf2f((unsigned short)(u >> 16));
        }
        *(float2*)(out + (size_t)v * D + lane * 2) = make_float2(a0, a1);
    }
}

// ================= round-3 fallback: atomic epilogue =================
__global__ __launch_bounds__(256) void edge1_mfma(
    const float* __restrict__ x, const unsigned short* __restrict__ Wt1,
    const int* __restrict__ src, const int* __restrict__ tgt,
    const int* __restrict__ sorted, const int* __restrict__ meta,
    float* __restrict__ out) {
    __shared__ uint4 As4[512];
    __shared__ int s_tgt[EPB];
    __shared__ int s_src[EPB];
    char* As = (char*)As4;

    int tid = threadIdx.x;
    int g0 = blockIdx.x * EPB;
    const int* pb = meta + 8;
    int t = 0;
#pragma unroll
    for (int k = 1; k < 4; k++)
        if (g0 >= pb[k]) t = k;
    const unsigned short* __restrict__ W = Wt1 + (size_t)t * D * D;

    if (tid < EPB) {
        int eid = sorted[g0 + tid];
        int sv = -1, tv = -1;
        if (eid >= 0) { sv = src[eid]; tv = tgt[eid]; }
        s_src[tid] = sv;
        s_tgt[tid] = tv;
    }
    __syncthreads();
    {
        int r = tid >> 3, u0 = tid & 7;
        int sv = s_src[r];
        const float4* srow = (const float4*)(x + (size_t)sv * D);
#pragma unroll
        for (int q = 0; q < 4; q++) {
            int u = u0 + 8 * q;
            float4 v = make_float4(0.f, 0.f, 0.f, 0.f);
            if (sv >= 0) v = srow[u];
            uint2 p;
            p.x = (unsigned)f2bf(v.x) | ((unsigned)f2bf(v.y) << 16);
            p.y = (unsigned)f2bf(v.z) | ((unsigned)f2bf(v.w) << 16);
            int byte = ((((u >> 1) * 16) ^ ((r & 7) << 4)) + (u & 1) * 8);
            *(uint2*)(As + r * 256 + byte) = p;
        }
    }
    __syncthreads();

    int wave = tid >> 6, lane = tid & 63;
    int c0 = wave * 32;
    int lrow = lane & 15, lgrp = lane >> 4;

    bf16x8 b[2][4];
#pragma unroll
    for (int fc = 0; fc < 2; fc++)
#pragma unroll
        for (int kk = 0; kk < 4; kk++)
            b[fc][kk] = *(const bf16x8*)(W + (size_t)(c0 + fc * 16 + lrow) * D +
                                         kk * 32 + lgrp * 8);

    f32x4 acc[2][2];
#pragma unroll
    for (int i = 0; i < 2; i++)
#pragma unroll
        for (int j = 0; j < 2; j++) acc[i][j] = (f32x4){0.f, 0.f, 0.f, 0.f};

#pragma unroll
    for (int kk = 0; kk < 4; kk++) {
        bf16x8 a0, a1;
        {
            int r = lrow;
            a0 = *(const bf16x8*)(As + r * 256 + ((kk * 64 + lgrp * 16) ^ ((r & 7) << 4)));
        }
        {
            int r = 16 + lrow;
            a1 = *(const bf16x8*)(As + r * 256 + ((kk * 64 + lgrp * 16) ^ ((r & 7) << 4)));
        }
        acc[0][0] = __builtin_amdgcn_mfma_f32_16x16x32_bf16(a0, b[0][kk], acc[0][0], 0, 0, 0);
        acc[1][0] = __builtin_amdgcn_mfma_f32_16x16x32_bf16(a1, b[0][kk], acc[1][0], 0, 0, 0);
        acc[0][1] = __builtin_amdgcn_mfma_f32_16x16x32_bf16(a0, b[1][kk], acc[0][1], 0, 0, 0);
        acc[1][1] = __builtin_amdgcn_mfma_f32_16x16x32_bf16(a1, b[1][kk], acc[1][1], 0, 0, 0);
    }

#pragma unroll
    for (int fr = 0; fr < 2; fr++)
#pragma unroll
        for (int reg = 0; reg < 4; reg++) {
            int erow = fr * 16 + lgrp * 4 + reg;
            int tv = s_tgt[erow];
            if (tv >= 0) {
#pragma unroll
                for (int fc = 0; fc < 2; fc++)
                    atomicAdd(&out[(size_t)tv * D + c0 + fc * 16 + lrow],
                              acc[fr][fc][reg]);
            }
        }
}

__global__ __launch_bounds__(256) void edge2_mfma(
    const float* __restrict__ x, const unsigned short* __restrict__ Wt2,
    const int* __restrict__ src2, const int* __restrict__ tgt,
    const int* __restrict__ sorted, const int* __restrict__ meta,
    float* __restrict__ out) {
    __shared__ uint4 As4[1024];
    __shared__ int s_tgt[EPB];
    __shared__ int s_srcA[EPB];
    __shared__ int s_srcB[EPB];
    char* As = (char*)As4;

    int tid = threadIdx.x;
    int g0 = blockIdx.x * EPB;
    const int* pb = meta + 13;
    int t = 0;
#pragma unroll
    for (int k = 1; k < 4; k++)
        if (g0 >= pb[k]) t = k;
    const unsigned short* __restrict__ W = Wt2 + (size_t)t * D * 2 * D;

    if (tid < EPB) {
        int eid = sorted[g0 + tid];
        int sa = -1, sb = -1, tv = -1;
        if (eid >= 0) { sa = src2[2 * eid]; sb = src2[2 * eid + 1]; tv = tgt[eid]; }
        s_srcA[tid] = sa;
        s_srcB[tid] = sb;
        s_tgt[tid] = tv;
    }
    __syncthreads();
    {
        int r = tid >> 3, u0 = tid & 7;
        int sa = s_srcA[r], sb = s_srcB[r];
        const float4* rowA = (const float4*)(x + (size_t)sa * D);
        const float4* rowB = (const float4*)(x + (size_t)sb * D);
#pragma unroll
        for (int q = 0; q < 8; q++) {
            int u = u0 + 8 * q;
            float4 v = make_float4(0.f, 0.f, 0.f, 0.f);
            if (sa >= 0) v = (u < 32) ? rowA[u] : rowB[u - 32];
            uint2 p;
            p.x = (unsigned)f2bf(v.x) | ((unsigned)f2bf(v.y) << 16);
            p.y = (unsigned)f2bf(v.z) | ((unsigned)f2bf(v.w) << 16);
            int byte = ((((u >> 1) * 16) ^ ((r & 7) << 4)) + (u & 1) * 8);
            *(uint2*)(As + r * 512 + byte) = p;
        }
    }
    __syncthreads();

    int wave = tid >> 6, lane = tid & 63;
    int c0 = wave * 32;
    int lrow = lane & 15, lgrp = lane >> 4;

    f32x4 acc[2][2];
#pragma unroll
    for (int i = 0; i < 2; i++)
#pragma unroll
        for (int j = 0; j < 2; j++) acc[i][j] = (f32x4){0.f, 0.f, 0.f, 0.f};

#pragma unroll
    for (int kk = 0; kk < 8; kk++) {
        bf16x8 b0 = *(const bf16x8*)(W + (size_t)(c0 + lrow) * 2 * D + kk * 32 + lgrp * 8);
        bf16x8 b1 = *(const bf16x8*)(W + (size_t)(c0 + 16 + lrow) * 2 * D + kk * 32 + lgrp * 8);
        bf16x8 a0, a1;
        {
            int r = lrow;
            a0 = *(const bf16x8*)(As + r * 512 + ((kk * 64 + lgrp * 16) ^ ((r & 7) << 4)));
        }
        {
            int r = 16 + lrow;
            a1 = *(const bf16x8*)(As + r * 512 + ((kk * 64 + lgrp * 16) ^ ((r & 7) << 4)));
        }
        acc[0][0] = __builtin_amdgcn_mfma_f32_16x16x32_bf16(a0, b0, acc[0][0], 0, 0, 0);
        acc[1][0] = __builtin_amdgcn_mfma_f32_16x16x32_bf16(a1, b0, acc[1][0], 0, 0, 0);
        acc[0][1] = __builtin_amdgcn_mfma_f32_16x16x32_bf16(a0, b1, acc[0][1], 0, 0, 0);
        acc[1][1] = __builtin_amdgcn_mfma_f32_16x16x32_bf16(a1, b1, acc[1][1], 0, 0, 0);
    }

#pragma unroll
    for (int fr = 0; fr < 2; fr++)
#pragma unroll
        for (int reg = 0; reg < 4; reg++) {
            int erow = fr * 16 + lgrp * 4 + reg;
            int tv = s_tgt[erow];
            if (tv >= 0) {
#pragma unroll
                for (int fc = 0; fc < 2; fc++)
                    atomicAdd(&out[(size_t)tv * D + c0 + fc * 16 + lrow],
                              acc[fr][fc][reg]);
            }
        }
}

// ---------------- simple fallback ----------------
__global__ __launch_bounds__(256) void e1_simple(
    const float* __restrict__ x, const float* __restrict__ W1,
    const int* __restrict__ src, const int* __restrict__ tgt,
    const int* __restrict__ type, float* __restrict__ out, int n) {
    int lane = threadIdx.x & 63;
    int wid = (blockIdx.x * blockDim.x + threadIdx.x) >> 6;
    int nw = (gridDim.x * blockDim.x) >> 6;
    for (int e = wid; e < n; e += nw) {
        const float* W = W1 + (size_t)type[e] * D * D;
        const float* xr = x + (size_t)src[e] * D;
        float a0 = 0.f, a1 = 0.f;
        for (int i = 0; i < D; i++) {
            float xv = xr[i];
            a0 = fmaf(xv, W[i * D + lane], a0);
            a1 = fmaf(xv, W[i * D + 64 + lane], a1);
        }
        atomicAdd(&out[(size_t)tgt[e] * D + lane], a0);
        atomicAdd(&out[(size_t)tgt[e] * D + 64 + lane], a1);
    }
}

__global__ __launch_bounds__(256) void e2_simple(
    const float* __restrict__ x, const float* __restrict__ W2,
    const int* __restrict__ src2, const int* __restrict__ tgt,
    const int* __restrict__ type, float* __restrict__ out, int n) {
    int lane = threadIdx.x & 63;
    int wid = (blockIdx.x * blockDim.x + threadIdx.x) >> 6;
    int nw = (gridDim.x * blockDim.x) >> 6;
    for (int e = wid; e < n; e += nw) {
        const float* W = W2 + (size_t)type[e] * 2 * D * D;
        const float* xrA = x + (size_t)src2[2 * e] * D;
        const float* xrB = x + (size_t)src2[2 * e + 1] * D;
        float a0 = 0.f, a1 = 0.f;
        for (int i = 0; i < 2 * D; i++) {
            float xv = (i < D) ? xrA[i] : xrB[i - D];
            a0 = fmaf(xv, W[i * D + lane], a0);
            a1 = fmaf(xv, W[i * D + 64 + lane], a1);
        }
        atomicAdd(&out[(size_t)tgt[e] * D + lane], a0);
        atomicAdd(&out[(size_t)tgt[e] * D + 64 + lane], a1);
    }
}

extern "C" void kernel_launch(void* const* d_in, const int* in_sizes, int n_in,
                              void* d_out, int out_size, void* d_ws, size_t ws_size,
                              hipStream_t stream) {
    const float* x = (const float*)d_in[0];
    const float* W1 = (const float*)d_in[1];
    const float* W2 = (const float*)d_in[2];
    const int* src1 = (const int*)d_in[3];
    const int* tgt1 = (const int*)d_in[4];
    const int* type1 = (const int*)d_in[5];
    const int* src2 = (const int*)d_in[6];
    const int* tgt2 = (const int*)d_in[7];
    const int* type2 = (const int*)d_in[8];
    float* out = (float*)d_out;

    int nn = in_sizes[0] / D;
    int E1c = in_sizes[3];
    int E2c = in_sizes[7];

    int grid1 = (E1c + 4 * (EPB - 1) + EPB - 1) / EPB;
    int grid2 = (E2c + 4 * (EPB - 1) + EPB - 1) / EPB;
    int cap1 = grid1 * EPB;
    int cap2 = grid2 * EPB;

    // int-region layout
    size_t o_meta = 0;
    size_t o_hist1 = o_meta + 32;
    size_t o_off1 = o_hist1 + (size_t)NB * 4;
    size_t o_hist2 = o_off1 + (size_t)NB * 4;
    size_t o_off2 = o_hist2 + (size_t)NB * 4;
    size_t o_sorted1 = o_off2 + (size_t)NB * 4;
    size_t o_sorted2 = o_sorted1 + cap1;
    size_t o_pos1 = o_sorted2 + cap2;
    size_t o_pos2 = o_pos1 + E1c;
    size_t o_cnt = o_pos2 + E2c;
    size_t o_base = o_cnt + nn;
    size_t ints_full = o_base + nn + 1;
    size_t ints_r3 = o_pos1;  // r3 path uses through sorted2

    size_t w1_elems = (size_t)4 * D * D;
    size_t w2_elems = (size_t)4 * D * 2 * D;

    size_t wb_full = (ints_full * 4 + 255) & ~(size_t)255;
    size_t wb_r3 = (ints_r3 * 4 + 255) & ~(size_t)255;
    size_t wt_bytes = (w1_elems + w2_elems) * 2;

    size_t msg_off = (wb_full + wt_bytes + 255) & ~(size_t)255;
    size_t msg_bytes = (size_t)(E1c + E2c) * D * 2;
    size_t need_full = msg_off + msg_bytes;
    size_t need_r3 = wb_r3 + wt_bytes;

    if (ws_size >= need_full) {
        int* wsI = (int*)d_ws;
        int* meta = wsI + o_meta;
        int* hist1 = wsI + o_hist1;
        int* off1 = wsI + o_off1;
        int* hist2 = wsI + o_hist2;
        int* off2 = wsI + o_off2;
        int* sorted1 = wsI + o_sorted1;
        int* sorted2 = wsI + o_sorted2;
        int* pos1 = wsI + o_pos1;
        int* pos2 = wsI + o_pos2;
        int* cnt = wsI + o_cnt;
        int* basep = wsI + o_base;
        unsigned short* wt1 = (unsigned short*)((char*)d_ws + wb_full);
        unsigned short* wt2 = wt1 + w1_elems;
        unsigned short* msg = (unsigned short*)((char*)d_ws + msg_off);

        hipMemsetAsync(sorted1, 0xFF, (size_t)4 * (cap1 + cap2), stream);
        hipMemsetAsync(cnt, 0, (size_t)4 * nn, stream);

        conv_w<<<dim3(4, 4, 4), 256, 0, stream>>>(W1, wt1, D);
        conv_w<<<dim3(8, 4, 4), 256, 0, stream>>>(W2, wt2, 2 * D);

        // type-sort
        hist_types<<<NB, 256, 0, stream>>>(type1, E1c, hist1);
        hist_types<<<NB, 256, 0, stream>>>(type2, E2c, hist2);
        scan_offsets<<<1, 64, 0, stream>>>(meta, hist1, off1, hist2, off2);
        write_sorted<<<NB, 256, 0, stream>>>(type1, E1c, off1, sorted1);
        write_sorted<<<NB, 256, 0, stream>>>(type2, E2c, off2, sorted2);

        // tgt slots
        assign_rel<<<2048, 256, 0, stream>>>(tgt1, E1c, cnt, pos1);
        assign_rel<<<2048, 256, 0, stream>>>(tgt2, E2c, cnt, pos2);
        scan_count<<<1, 1024, 0, stream>>>(cnt, nn, basep);

        // phase 1: messages
        edge1_msg<<<grid1, 256, 0, stream>>>(x, wt1, src1, tgt1, sorted1, meta,
                                             basep, pos1, msg);
        edge2_msg<<<grid2, 256, 0, stream>>>(x, wt2, src2, tgt2, sorted2, meta,
                                             basep, pos2, msg);

        // phase 2
        finalize<<<(nn + 3) / 4, 256, 0, stream>>>(x, msg, basep, out, nn);
    } else if (ws_size >= need_r3) {
        int* wsI = (int*)d_ws;
        int* meta = wsI + o_meta;
        int* hist1 = wsI + o_hist1;
        int* off1 = wsI + o_off1;
        int* hist2 = wsI + o_hist2;
        int* off2 = wsI + o_off2;
        int* sorted1 = wsI + o_sorted1;
        int* sorted2 = wsI + o_sorted2;
        unsigned short* wt1 = (unsigned short*)((char*)d_ws + wb_r3);
        unsigned short* wt2 = wt1 + w1_elems;

        copy_kernel<<<2048, 256, 0, stream>>>(out, x, nn * D);
        hipMemsetAsync(sorted1, 0xFF, (size_t)4 * (cap1 + cap2), stream);

        conv_w<<<dim3(4, 4, 4), 256, 0, stream>>>(W1, wt1, D);
        conv_w<<<dim3(8, 4, 4), 256, 0, stream>>>(W2, wt2, 2 * D);

        hist_types<<<NB, 256, 0, stream>>>(type1, E1c, hist1);
        hist_types<<<NB, 256, 0, stream>>>(type2, E2c, hist2);
        scan_offsets<<<1, 64, 0, stream>>>(meta, hist1, off1, hist2, off2);
        write_sorted<<<NB, 256, 0, stream>>>(type1, E1c, off1, sorted1);
        write_sorted<<<NB, 256, 0, stream>>>(type2, E2c, off2, sorted2);

        edge1_mfma<<<grid1, 256, 0, stream>>>(x, wt1, src1, tgt1, sorted1, meta, out);
        edge2_mfma<<<grid2, 256, 0, stream>>>(x, wt2, src2, tgt2, sorted2, meta, out);
    } else {
        copy_kernel<<<2048, 256, 0, stream>>>(out, x, nn * D);
        e1_simple<<<2048, 256, 0, stream>>>(x, W1, src1, tgt1, type1, out, E1c);
        e2_simple<<<2048, 256, 0, stream>>>(x, W2, src2, tgt2, type2, out, E2c);
    }
}

// Round 5
// 344.039 us; speedup vs baseline: 1.4437x; 1.4437x over previous
//
#include <hip/hip_runtime.h>
#include <hip/hip_bf16.h>

#define D 128
#define EPB 32   // edges per block (MFMA kernels)
#define NB 256   // blocks for hist/write passes

typedef __attribute__((ext_vector_type(8))) short bf16x8;
typedef __attribute__((ext_vector_type(4))) float f32x4;

__device__ inline unsigned short f2bf(float f) {
    union { float f; unsigned int u; } v;
    v.f = f;
    unsigned int u = v.u;
    unsigned int r = u + 0x7fffu + ((u >> 16) & 1u);  // RNE
    return (unsigned short)(r >> 16);
}
__device__ inline float bf2f(unsigned short b) {
    union { unsigned int u; float f; } v;
    v.u = ((unsigned int)b) << 16;
    return v.f;
}

// ---------------- out = x (fallback paths only) ----------------
__global__ __launch_bounds__(256) void copy_kernel(float* __restrict__ out,
                                                   const float* __restrict__ x,
                                                   int n_elems) {
    int n4 = n_elems >> 2;
    const float4* src = (const float4*)x;
    float4* dst = (float4*)out;
    for (int i = blockIdx.x * blockDim.x + threadIdx.x; i < n4;
         i += gridDim.x * blockDim.x)
        dst[i] = src[i];
}

// ---------------- W[t][k][c] fp32 -> Wt[t][c][k] bf16 ----------------
__global__ __launch_bounds__(256) void conv_w(const float* __restrict__ W,
                                              unsigned short* __restrict__ Wt,
                                              int K) {
    __shared__ float tile[32][33];
    int k0 = blockIdx.x * 32, c0 = blockIdx.y * 32, t = blockIdx.z;
    int tr = threadIdx.x >> 5, tc = threadIdx.x & 31;
#pragma unroll
    for (int m = 0; m < 4; m++)
        tile[m * 8 + tr][tc] = W[((size_t)t * K + k0 + m * 8 + tr) * D + c0 + tc];
    __syncthreads();
#pragma unroll
    for (int m = 0; m < 4; m++)
        Wt[((size_t)t * D + c0 + m * 8 + tr) * K + k0 + tc] = f2bf(tile[tc][m * 8 + tr]);
}

// ---------------- type-sort pass 1: per-block histogram ----------------
__global__ __launch_bounds__(256) void hist_types(const int* __restrict__ type,
                                                  int n, int* __restrict__ hist) {
    __shared__ int h[4];
    if (threadIdx.x < 4) h[threadIdx.x] = 0;
    __syncthreads();
    for (int i = blockIdx.x * 256 + threadIdx.x; i < n; i += NB * 256)
        atomicAdd(&h[type[i]], 1);
    __syncthreads();
    if (threadIdx.x < 4) hist[blockIdx.x * 4 + threadIdx.x] = h[threadIdx.x];
}

// meta: [0..3]=total1, [4..7]=total2, [8..12]=pb1, [13..17]=pb2
__global__ void scan_offsets(int* __restrict__ meta,
                             const int* __restrict__ hist1, int* __restrict__ off1,
                             const int* __restrict__ hist2, int* __restrict__ off2) {
    int t = threadIdx.x;
    if (t < 4) {
        int s = 0;
        for (int b = 0; b < NB; b++) s += hist1[b * 4 + t];
        meta[t] = s;
    } else if (t < 8) {
        int tt = t - 4, s = 0;
        for (int b = 0; b < NB; b++) s += hist2[b * 4 + tt];
        meta[4 + tt] = s;
    }
    __syncthreads();
    if (t == 0) {
        int p = 0;
        for (int k = 0; k < 4; k++) {
            meta[8 + k] = p;
            p += ((meta[k] + EPB - 1) / EPB) * EPB;
        }
        meta[12] = p;
        p = 0;
        for (int k = 0; k < 4; k++) {
            meta[13 + k] = p;
            p += ((meta[4 + k] + EPB - 1) / EPB) * EPB;
        }
        meta[17] = p;
    }
    __syncthreads();
    if (t < 4) {
        int p = meta[8 + t];
        for (int b = 0; b < NB; b++) { off1[b * 4 + t] = p; p += hist1[b * 4 + t]; }
    } else if (t < 8) {
        int tt = t - 4;
        int p = meta[13 + tt];
        for (int b = 0; b < NB; b++) { off2[b * 4 + tt] = p; p += hist2[b * 4 + tt]; }
    }
}

__global__ __launch_bounds__(256) void write_sorted(const int* __restrict__ type,
                                                    int n,
                                                    const int* __restrict__ off,
                                                    int* __restrict__ sorted) {
    __shared__ int loff[4];
    if (threadIdx.x < 4) loff[threadIdx.x] = off[blockIdx.x * 4 + threadIdx.x];
    __syncthreads();
    for (int i = blockIdx.x * 256 + threadIdx.x; i < n; i += NB * 256) {
        int t = type[i];
        int pos = atomicAdd(&loff[t], 1);
        sorted[pos] = i;
    }
}

// ---------------- tgt machinery: slot assignment + multi-block scan ----------------
__global__ __launch_bounds__(256) void assign_rel(const int* __restrict__ tgt, int n,
                                                  int* __restrict__ cnt,
                                                  int* __restrict__ pos) {
    for (int i = blockIdx.x * blockDim.x + threadIdx.x; i < n;
         i += gridDim.x * blockDim.x)
        pos[i] = atomicAdd(&cnt[tgt[i]], 1);
}

// pass 1: per-512-chunk local exclusive prefix into base, chunk total into bsum
__global__ __launch_bounds__(256) void scan_pass1(const int* __restrict__ cnt, int n,
                                                  int* __restrict__ base,
                                                  int* __restrict__ bsum) {
    __shared__ int s[256];
    int b = blockIdx.x, t = threadIdx.x;
    int i0 = b * 512 + 2 * t;
    int v0 = (i0 < n) ? cnt[i0] : 0;
    int v1 = (i0 + 1 < n) ? cnt[i0 + 1] : 0;
    s[t] = v0 + v1;
    __syncthreads();
    for (int off = 1; off < 256; off <<= 1) {
        int v = s[t];
        int u = (t >= off) ? s[t - off] : 0;
        __syncthreads();
        s[t] = v + u;
        __syncthreads();
    }
    int excl = (t > 0) ? s[t - 1] : 0;
    if (i0 < n) base[i0] = excl;
    if (i0 + 1 < n) base[i0 + 1] = excl + v0;
    if (t == 255) bsum[b] = s[255];
}

// pass 2: scan block sums (1 block, handles any nb), append grand total at bsum[nb]
__global__ __launch_bounds__(256) void scan_pass2(int* __restrict__ bsum, int nb) {
    __shared__ int s[256];
    int t = threadIdx.x;
    int run = 0;
    for (int b0 = 0; b0 < nb; b0 += 256) {
        int v = (b0 + t < nb) ? bsum[b0 + t] : 0;
        s[t] = v;
        __syncthreads();
        for (int off = 1; off < 256; off <<= 1) {
            int a = s[t];
            int u = (t >= off) ? s[t - off] : 0;
            __syncthreads();
            s[t] = a + u;
            __syncthreads();
        }
        if (b0 + t < nb) bsum[b0 + t] = run + ((t > 0) ? s[t - 1] : 0);
        int tot = s[255];
        __syncthreads();
        run += tot;
    }
    if (t == 0) bsum[nb] = run;
}

// pass 3: add block offsets; write base[n] = total
__global__ __launch_bounds__(256) void scan_pass3(int* __restrict__ base,
                                                  const int* __restrict__ bsum, int n) {
    int i = blockIdx.x * 256 + threadIdx.x;
    if (i < n) base[i] += bsum[i >> 9];
    else if (i == n) base[n] = bsum[(n + 511) >> 9];
}

// ================= MFMA edge kernels (message-writing) =================
__global__ __launch_bounds__(256) void edge1_msg(
    const float* __restrict__ x, const unsigned short* __restrict__ Wt1,
    const int* __restrict__ src, const int* __restrict__ tgt,
    const int* __restrict__ sorted, const int* __restrict__ meta,
    const int* __restrict__ basep, const int* __restrict__ pos,
    unsigned short* __restrict__ msg) {
    __shared__ uint4 As4[512];
    __shared__ int s_mrow[EPB];
    __shared__ int s_src[EPB];
    char* As = (char*)As4;

    int tid = threadIdx.x;
    int g0 = blockIdx.x * EPB;
    const int* pb = meta + 8;
    int t = 0;
#pragma unroll
    for (int k = 1; k < 4; k++)
        if (g0 >= pb[k]) t = k;
    const unsigned short* __restrict__ W = Wt1 + (size_t)t * D * D;

    if (tid < EPB) {
        int eid = sorted[g0 + tid];
        int sv = -1, mr = -1;
        if (eid >= 0) { sv = src[eid]; mr = basep[tgt[eid]] + pos[eid]; }
        s_src[tid] = sv;
        s_mrow[tid] = mr;
    }
    __syncthreads();

    {
        int r = tid >> 3, u0 = tid & 7;
        int sv = s_src[r];
        const float4* srow = (const float4*)(x + (size_t)sv * D);
#pragma unroll
        for (int q = 0; q < 4; q++) {
            int u = u0 + 8 * q;
            float4 v = make_float4(0.f, 0.f, 0.f, 0.f);
            if (sv >= 0) v = srow[u];
            uint2 p;
            p.x = (unsigned)f2bf(v.x) | ((unsigned)f2bf(v.y) << 16);
            p.y = (unsigned)f2bf(v.z) | ((unsigned)f2bf(v.w) << 16);
            int byte = ((((u >> 1) * 16) ^ ((r & 7) << 4)) + (u & 1) * 8);
            *(uint2*)(As + r * 256 + byte) = p;
        }
    }
    __syncthreads();

    int wave = tid >> 6, lane = tid & 63;
    int c0 = wave * 32;
    int lrow = lane & 15, lgrp = lane >> 4;

    bf16x8 b[2][4];
#pragma unroll
    for (int fc = 0; fc < 2; fc++)
#pragma unroll
        for (int kk = 0; kk < 4; kk++)
            b[fc][kk] = *(const bf16x8*)(W + (size_t)(c0 + fc * 16 + lrow) * D +
                                         kk * 32 + lgrp * 8);

    f32x4 acc[2][2];
#pragma unroll
    for (int i = 0; i < 2; i++)
#pragma unroll
        for (int j = 0; j < 2; j++) acc[i][j] = (f32x4){0.f, 0.f, 0.f, 0.f};

#pragma unroll
    for (int kk = 0; kk < 4; kk++) {
        bf16x8 a0, a1;
        {
            int r = lrow;
            a0 = *(const bf16x8*)(As + r * 256 +
                                  ((kk * 64 + lgrp * 16) ^ ((r & 7) << 4)));
        }
        {
            int r = 16 + lrow;
            a1 = *(const bf16x8*)(As + r * 256 +
                                  ((kk * 64 + lgrp * 16) ^ ((r & 7) << 4)));
        }
        acc[0][0] = __builtin_amdgcn_mfma_f32_16x16x32_bf16(a0, b[0][kk], acc[0][0], 0, 0, 0);
        acc[1][0] = __builtin_amdgcn_mfma_f32_16x16x32_bf16(a1, b[0][kk], acc[1][0], 0, 0, 0);
        acc[0][1] = __builtin_amdgcn_mfma_f32_16x16x32_bf16(a0, b[1][kk], acc[0][1], 0, 0, 0);
        acc[1][1] = __builtin_amdgcn_mfma_f32_16x16x32_bf16(a1, b[1][kk], acc[1][1], 0, 0, 0);
    }

#pragma unroll
    for (int fr = 0; fr < 2; fr++)
#pragma unroll
        for (int reg = 0; reg < 4; reg++) {
            int erow = fr * 16 + lgrp * 4 + reg;
            int mr = s_mrow[erow];
            if (mr >= 0) {
#pragma unroll
                for (int fc = 0; fc < 2; fc++)
                    msg[(size_t)mr * D + c0 + fc * 16 + lrow] =
                        f2bf(acc[fr][fc][reg]);
            }
        }
}

__global__ __launch_bounds__(256) void edge2_msg(
    const float* __restrict__ x, const unsigned short* __restrict__ Wt2,
    const int* __restrict__ src2, const int* __restrict__ tgt,
    const int* __restrict__ sorted, const int* __restrict__ meta,
    const int* __restrict__ basep, const int* __restrict__ pos,
    unsigned short* __restrict__ msg) {
    __shared__ uint4 As4[1024];
    __shared__ int s_mrow[EPB];
    __shared__ int s_srcA[EPB];
    __shared__ int s_srcB[EPB];
    char* As = (char*)As4;

    int tid = threadIdx.x;
    int g0 = blockIdx.x * EPB;
    const int* pb = meta + 13;
    int t = 0;
#pragma unroll
    for (int k = 1; k < 4; k++)
        if (g0 >= pb[k]) t = k;
    const unsigned short* __restrict__ W = Wt2 + (size_t)t * D * 2 * D;

    if (tid < EPB) {
        int eid = sorted[g0 + tid];
        int sa = -1, sb = -1, mr = -1;
        if (eid >= 0) {
            sa = src2[2 * eid];
            sb = src2[2 * eid + 1];
            mr = basep[tgt[eid]] + pos[eid];
        }
        s_srcA[tid] = sa;
        s_srcB[tid] = sb;
        s_mrow[tid] = mr;
    }
    __syncthreads();

    {
        int r = tid >> 3, u0 = tid & 7;
        int sa = s_srcA[r], sb = s_srcB[r];
        const float4* rowA = (const float4*)(x + (size_t)sa * D);
        const float4* rowB = (const float4*)(x + (size_t)sb * D);
#pragma unroll
        for (int q = 0; q < 8; q++) {
            int u = u0 + 8 * q;
            float4 v = make_float4(0.f, 0.f, 0.f, 0.f);
            if (sa >= 0) v = (u < 32) ? rowA[u] : rowB[u - 32];
            uint2 p;
            p.x = (unsigned)f2bf(v.x) | ((unsigned)f2bf(v.y) << 16);
            p.y = (unsigned)f2bf(v.z) | ((unsigned)f2bf(v.w) << 16);
            int byte = ((((u >> 1) * 16) ^ ((r & 7) << 4)) + (u & 1) * 8);
            *(uint2*)(As + r * 512 + byte) = p;
        }
    }
    __syncthreads();

    int wave = tid >> 6, lane = tid & 63;
    int c0 = wave * 32;
    int lrow = lane & 15, lgrp = lane >> 4;

    f32x4 acc[2][2];
#pragma unroll
    for (int i = 0; i < 2; i++)
#pragma unroll
        for (int j = 0; j < 2; j++) acc[i][j] = (f32x4){0.f, 0.f, 0.f, 0.f};

#pragma unroll
    for (int kk = 0; kk < 8; kk++) {
        bf16x8 b0 = *(const bf16x8*)(W + (size_t)(c0 + lrow) * 2 * D + kk * 32 + lgrp * 8);
        bf16x8 b1 = *(const bf16x8*)(W + (size_t)(c0 + 16 + lrow) * 2 * D + kk * 32 + lgrp * 8);
        bf16x8 a0, a1;
        {
            int r = lrow;
            a0 = *(const bf16x8*)(As + r * 512 +
                                  ((kk * 64 + lgrp * 16) ^ ((r & 7) << 4)));
        }
        {
            int r = 16 + lrow;
            a1 = *(const bf16x8*)(As + r * 512 +
                                  ((kk * 64 + lgrp * 16) ^ ((r & 7) << 4)));
        }
        acc[0][0] = __builtin_amdgcn_mfma_f32_16x16x32_bf16(a0, b0, acc[0][0], 0, 0, 0);
        acc[1][0] = __builtin_amdgcn_mfma_f32_16x16x32_bf16(a1, b0, acc[1][0], 0, 0, 0);
        acc[0][1] = __builtin_amdgcn_mfma_f32_16x16x32_bf16(a0, b1, acc[0][1], 0, 0, 0);
        acc[1][1] = __builtin_amdgcn_mfma_f32_16x16x32_bf16(a1, b1, acc[1][1], 0, 0, 0);
    }

#pragma unroll
    for (int fr = 0; fr < 2; fr++)
#pragma unroll
        for (int reg = 0; reg < 4; reg++) {
            int erow = fr * 16 + lgrp * 4 + reg;
            int mr = s_mrow[erow];
            if (mr >= 0) {
#pragma unroll
                for (int fc = 0; fc < 2; fc++)
                    msg[(size_t)mr * D + c0 + fc * 16 + lrow] =
                        f2bf(acc[fr][fc][reg]);
            }
        }
}

// ---------------- phase 2: out = x + contiguous segment sum ----------------
__global__ __launch_bounds__(256) void finalize(
    const float* __restrict__ x, const unsigned short* __restrict__ msg,
    const int* __restrict__ basep, float* __restrict__ out, int nn) {
    int wib = threadIdx.x >> 6, lane = threadIdx.x & 63;
    for (int v = blockIdx.x * 4 + wib; v < nn; v += gridDim.x * 4) {
        int b0 = basep[v], b1 = basep[v + 1];
        float2 xv = *(const float2*)(x + (size_t)v * D + lane * 2);
        float a0 = xv.x, a1 = xv.y;
        for (int i = b0; i < b1; i++) {
            unsigned u = *(const unsigned*)(msg + (size_t)i * D + lane * 2);
            a0 += bf2f((unsigned short)(u & 0xffff));
            a1 += bf2f((unsigned short)(u >> 16));
        }
        *(float2*)(out + (size_t)v * D + lane * 2) = make_float2(a0, a1);
    }
}

// ================= round-3 fallback: atomic epilogue =================
__global__ __launch_bounds__(256) void edge1_mfma(
    const float* __restrict__ x, const unsigned short* __restrict__ Wt1,
    const int* __restrict__ src, const int* __restrict__ tgt,
    const int* __restrict__ sorted, const int* __restrict__ meta,
    float* __restrict__ out) {
    __shared__ uint4 As4[512];
    __shared__ int s_tgt[EPB];
    __shared__ int s_src[EPB];
    char* As = (char*)As4;

    int tid = threadIdx.x;
    int g0 = blockIdx.x * EPB;
    const int* pb = meta + 8;
    int t = 0;
#pragma unroll
    for (int k = 1; k < 4; k++)
        if (g0 >= pb[k]) t = k;
    const unsigned short* __restrict__ W = Wt1 + (size_t)t * D * D;

    if (tid < EPB) {
        int eid = sorted[g0 + tid];
        int sv = -1, tv = -1;
        if (eid >= 0) { sv = src[eid]; tv = tgt[eid]; }
        s_src[tid] = sv;
        s_tgt[tid] = tv;
    }
    __syncthreads();
    {
        int r = tid >> 3, u0 = tid & 7;
        int sv = s_src[r];
        const float4* srow = (const float4*)(x + (size_t)sv * D);
#pragma unroll
        for (int q = 0; q < 4; q++) {
            int u = u0 + 8 * q;
            float4 v = make_float4(0.f, 0.f, 0.f, 0.f);
            if (sv >= 0) v = srow[u];
            uint2 p;
            p.x = (unsigned)f2bf(v.x) | ((unsigned)f2bf(v.y) << 16);
            p.y = (unsigned)f2bf(v.z) | ((unsigned)f2bf(v.w) << 16);
            int byte = ((((u >> 1) * 16) ^ ((r & 7) << 4)) + (u & 1) * 8);
            *(uint2*)(As + r * 256 + byte) = p;
        }
    }
    __syncthreads();

    int wave = tid >> 6, lane = tid & 63;
    int c0 = wave * 32;
    int lrow = lane & 15, lgrp = lane >> 4;

    bf16x8 b[2][4];
#pragma unroll
    for (int fc = 0; fc < 2; fc++)
#pragma unroll
        for (int kk = 0; kk < 4; kk++)
            b[fc][kk] = *(const bf16x8*)(W + (size_t)(c0 + fc * 16 + lrow) * D +
                                         kk * 32 + lgrp * 8);

    f32x4 acc[2][2];
#pragma unroll
    for (int i = 0; i < 2; i++)
#pragma unroll
        for (int j = 0; j < 2; j++) acc[i][j] = (f32x4){0.f, 0.f, 0.f, 0.f};

#pragma unroll
    for (int kk = 0; kk < 4; kk++) {
        bf16x8 a0, a1;
        {
            int r = lrow;
            a0 = *(const bf16x8*)(As + r * 256 + ((kk * 64 + lgrp * 16) ^ ((r & 7) << 4)));
        }
        {
            int r = 16 + lrow;
            a1 = *(const bf16x8*)(As + r * 256 + ((kk * 64 + lgrp * 16) ^ ((r & 7) << 4)));
        }
        acc[0][0] = __builtin_amdgcn_mfma_f32_16x16x32_bf16(a0, b[0][kk], acc[0][0], 0, 0, 0);
        acc[1][0] = __builtin_amdgcn_mfma_f32_16x16x32_bf16(a1, b[0][kk], acc[1][0], 0, 0, 0);
        acc[0][1] = __builtin_amdgcn_mfma_f32_16x16x32_bf16(a0, b[1][kk], acc[0][1], 0, 0, 0);
        acc[1][1] = __builtin_amdgcn_mfma_f32_16x16x32_bf16(a1, b[1][kk], acc[1][1], 0, 0, 0);
    }

#pragma unroll
    for (int fr = 0; fr < 2; fr++)
#pragma unroll
        for (int reg = 0; reg < 4; reg++) {
            int erow = fr * 16 + lgrp * 4 + reg;
            int tv = s_tgt[erow];
            if (tv >= 0) {
#pragma unroll
                for (int fc = 0; fc < 2; fc++)
                    atomicAdd(&out[(size_t)tv * D + c0 + fc * 16 + lrow],
                              acc[fr][fc][reg]);
            }
        }
}

__global__ __launch_bounds__(256) void edge2_mfma(
    const float* __restrict__ x, const unsigned short* __restrict__ Wt2,
    const int* __restrict__ src2, const int* __restrict__ tgt,
    const int* __restrict__ sorted, const int* __restrict__ meta,
    float* __restrict__ out) {
    __shared__ uint4 As4[1024];
    __shared__ int s_tgt[EPB];
    __shared__ int s_srcA[EPB];
    __shared__ int s_srcB[EPB];
    char* As = (char*)As4;

    int tid = threadIdx.x;
    int g0 = blockIdx.x * EPB;
    const int* pb = meta + 13;
    int t = 0;
#pragma unroll
    for (int k = 1; k < 4; k++)
        if (g0 >= pb[k]) t = k;
    const unsigned short* __restrict__ W = Wt2 + (size_t)t * D * 2 * D;

    if (tid < EPB) {
        int eid = sorted[g0 + tid];
        int sa = -1, sb = -1, tv = -1;
        if (eid >= 0) { sa = src2[2 * eid]; sb = src2[2 * eid + 1]; tv = tgt[eid]; }
        s_srcA[tid] = sa;
        s_srcB[tid] = sb;
        s_tgt[tid] = tv;
    }
    __syncthreads();
    {
        int r = tid >> 3, u0 = tid & 7;
        int sa = s_srcA[r], sb = s_srcB[r];
        const float4* rowA = (const float4*)(x + (size_t)sa * D);
        const float4* rowB = (const float4*)(x + (size_t)sb * D);
#pragma unroll
        for (int q = 0; q < 8; q++) {
            int u = u0 + 8 * q;
            float4 v = make_float4(0.f, 0.f, 0.f, 0.f);
            if (sa >= 0) v = (u < 32) ? rowA[u] : rowB[u - 32];
            uint2 p;
            p.x = (unsigned)f2bf(v.x) | ((unsigned)f2bf(v.y) << 16);
            p.y = (unsigned)f2bf(v.z) | ((unsigned)f2bf(v.w) << 16);
            int byte = ((((u >> 1) * 16) ^ ((r & 7) << 4)) + (u & 1) * 8);
            *(uint2*)(As + r * 512 + byte) = p;
        }
    }
    __syncthreads();

    int wave = tid >> 6, lane = tid & 63;
    int c0 = wave * 32;
    int lrow = lane & 15, lgrp = lane >> 4;

    f32x4 acc[2][2];
#pragma unroll
    for (int i = 0; i < 2; i++)
#pragma unroll
        for (int j = 0; j < 2; j++) acc[i][j] = (f32x4){0.f, 0.f, 0.f, 0.f};

#pragma unroll
    for (int kk = 0; kk < 8; kk++) {
        bf16x8 b0 = *(const bf16x8*)(W + (size_t)(c0 + lrow) * 2 * D + kk * 32 + lgrp * 8);
        bf16x8 b1 = *(const bf16x8*)(W + (size_t)(c0 + 16 + lrow) * 2 * D + kk * 32 + lgrp * 8);
        bf16x8 a0, a1;
        {
            int r = lrow;
            a0 = *(const bf16x8*)(As + r * 512 + ((kk * 64 + lgrp * 16) ^ ((r & 7) << 4)));
        }
        {
            int r = 16 + lrow;
            a1 = *(const bf16x8*)(As + r * 512 + ((kk * 64 + lgrp * 16) ^ ((r & 7) << 4)));
        }
        acc[0][0] = __builtin_amdgcn_mfma_f32_16x16x32_bf16(a0, b0, acc[0][0], 0, 0, 0);
        acc[1][0] = __builtin_amdgcn_mfma_f32_16x16x32_bf16(a1, b0, acc[1][0], 0, 0, 0);
        acc[0][1] = __builtin_amdgcn_mfma_f32_16x16x32_bf16(a0, b1, acc[0][1], 0, 0, 0);
        acc[1][1] = __builtin_amdgcn_mfma_f32_16x16x32_bf16(a1, b1, acc[1][1], 0, 0, 0);
    }

#pragma unroll
    for (int fr = 0; fr < 2; fr++)
#pragma unroll
        for (int reg = 0; reg < 4; reg++) {
            int erow = fr * 16 + lgrp * 4 + reg;
            int tv = s_tgt[erow];
            if (tv >= 0) {
#pragma unroll
                for (int fc = 0; fc < 2; fc++)
                    atomicAdd(&out[(size_t)tv * D + c0 + fc * 16 + lrow],
                              acc[fr][fc][reg]);
            }
        }
}

// ---------------- simple fallback ----------------
__global__ __launch_bounds__(256) void e1_simple(
    const float* __restrict__ x, const float* __restrict__ W1,
    const int* __restrict__ src, const int* __restrict__ tgt,
    const int* __restrict__ type, float* __restrict__ out, int n) {
    int lane = threadIdx.x & 63;
    int wid = (blockIdx.x * blockDim.x + threadIdx.x) >> 6;
    int nw = (gridDim.x * blockDim.x) >> 6;
    for (int e = wid; e < n; e += nw) {
        const float* W = W1 + (size_t)type[e] * D * D;
        const float* xr = x + (size_t)src[e] * D;
        float a0 = 0.f, a1 = 0.f;
        for (int i = 0; i < D; i++) {
            float xv = xr[i];
            a0 = fmaf(xv, W[i * D + lane], a0);
            a1 = fmaf(xv, W[i * D + 64 + lane], a1);
        }
        atomicAdd(&out[(size_t)tgt[e] * D + lane], a0);
        atomicAdd(&out[(size_t)tgt[e] * D + 64 + lane], a1);
    }
}

__global__ __launch_bounds__(256) void e2_simple(
    const float* __restrict__ x, const float* __restrict__ W2,
    const int* __restrict__ src2, const int* __restrict__ tgt,
    const int* __restrict__ type, float* __restrict__ out, int n) {
    int lane = threadIdx.x & 63;
    int wid = (blockIdx.x * blockDim.x + threadIdx.x) >> 6;
    int nw = (gridDim.x * blockDim.x) >> 6;
    for (int e = wid; e < n; e += nw) {
        const float* W = W2 + (size_t)type[e] * 2 * D * D;
        const float* xrA = x + (size_t)src2[2 * e] * D;
        const float* xrB = x + (size_t)src2[2 * e + 1] * D;
        float a0 = 0.f, a1 = 0.f;
        for (int i = 0; i < 2 * D; i++) {
            float xv = (i < D) ? xrA[i] : xrB[i - D];
            a0 = fmaf(xv, W[i * D + lane], a0);
            a1 = fmaf(xv, W[i * D + 64 + lane], a1);
        }
        atomicAdd(&out[(size_t)tgt[e] * D + lane], a0);
        atomicAdd(&out[(size_t)tgt[e] * D + 64 + lane], a1);
    }
}

extern "C" void kernel_launch(void* const* d_in, const int* in_sizes, int n_in,
                              void* d_out, int out_size, void* d_ws, size_t ws_size,
                              hipStream_t stream) {
    const float* x = (const float*)d_in[0];
    const float* W1 = (const float*)d_in[1];
    const float* W2 = (const float*)d_in[2];
    const int* src1 = (const int*)d_in[3];
    const int* tgt1 = (const int*)d_in[4];
    const int* type1 = (const int*)d_in[5];
    const int* src2 = (const int*)d_in[6];
    const int* tgt2 = (const int*)d_in[7];
    const int* type2 = (const int*)d_in[8];
    float* out = (float*)d_out;

    int nn = in_sizes[0] / D;
    int E1c = in_sizes[3];
    int E2c = in_sizes[7];

    int grid1 = (E1c + 4 * (EPB - 1) + EPB - 1) / EPB;
    int grid2 = (E2c + 4 * (EPB - 1) + EPB - 1) / EPB;
    int cap1 = grid1 * EPB;
    int cap2 = grid2 * EPB;
    int nb_scan = (nn + 511) / 512;

    // int-region layout
    size_t o_meta = 0;
    size_t o_hist1 = o_meta + 32;
    size_t o_off1 = o_hist1 + (size_t)NB * 4;
    size_t o_hist2 = o_off1 + (size_t)NB * 4;
    size_t o_off2 = o_hist2 + (size_t)NB * 4;
    size_t o_sorted1 = o_off2 + (size_t)NB * 4;
    size_t o_sorted2 = o_sorted1 + cap1;
    size_t o_pos1 = o_sorted2 + cap2;
    size_t o_pos2 = o_pos1 + E1c;
    size_t o_cnt = o_pos2 + E2c;
    size_t o_base = o_cnt + nn;
    size_t o_bsum = o_base + nn + 1;
    size_t ints_full = o_bsum + nb_scan + 1;
    size_t ints_r3 = o_pos1;  // r3 path uses through sorted2

    size_t w1_elems = (size_t)4 * D * D;
    size_t w2_elems = (size_t)4 * D * 2 * D;

    size_t wb_full = (ints_full * 4 + 255) & ~(size_t)255;
    size_t wb_r3 = (ints_r3 * 4 + 255) & ~(size_t)255;
    size_t wt_bytes = (w1_elems + w2_elems) * 2;

    size_t msg_off = (wb_full + wt_bytes + 255) & ~(size_t)255;
    size_t msg_bytes = (size_t)(E1c + E2c) * D * 2;
    size_t need_full = msg_off + msg_bytes;
    size_t need_r3 = wb_r3 + wt_bytes;

    if (ws_size >= need_full) {
        int* wsI = (int*)d_ws;
        int* meta = wsI + o_meta;
        int* hist1 = wsI + o_hist1;
        int* off1 = wsI + o_off1;
        int* hist2 = wsI + o_hist2;
        int* off2 = wsI + o_off2;
        int* sorted1 = wsI + o_sorted1;
        int* sorted2 = wsI + o_sorted2;
        int* pos1 = wsI + o_pos1;
        int* pos2 = wsI + o_pos2;
        int* cnt = wsI + o_cnt;
        int* basep = wsI + o_base;
        int* bsum = wsI + o_bsum;
        unsigned short* wt1 = (unsigned short*)((char*)d_ws + wb_full);
        unsigned short* wt2 = wt1 + w1_elems;
        unsigned short* msg = (unsigned short*)((char*)d_ws + msg_off);

        hipMemsetAsync(sorted1, 0xFF, (size_t)4 * (cap1 + cap2), stream);
        hipMemsetAsync(cnt, 0, (size_t)4 * nn, stream);

        conv_w<<<dim3(4, 4, 4), 256, 0, stream>>>(W1, wt1, D);
        conv_w<<<dim3(8, 4, 4), 256, 0, stream>>>(W2, wt2, 2 * D);

        // type-sort
        hist_types<<<NB, 256, 0, stream>>>(type1, E1c, hist1);
        hist_types<<<NB, 256, 0, stream>>>(type2, E2c, hist2);
        scan_offsets<<<1, 64, 0, stream>>>(meta, hist1, off1, hist2, off2);
        write_sorted<<<NB, 256, 0, stream>>>(type1, E1c, off1, sorted1);
        write_sorted<<<NB, 256, 0, stream>>>(type2, E2c, off2, sorted2);

        // tgt slots
        assign_rel<<<2048, 256, 0, stream>>>(tgt1, E1c, cnt, pos1);
        assign_rel<<<2048, 256, 0, stream>>>(tgt2, E2c, cnt, pos2);
        scan_pass1<<<nb_scan, 256, 0, stream>>>(cnt, nn, basep, bsum);
        scan_pass2<<<1, 256, 0, stream>>>(bsum, nb_scan);
        scan_pass3<<<(nn + 1 + 255) / 256, 256, 0, stream>>>(basep, bsum, nn);

        // phase 1: messages
        edge1_msg<<<grid1, 256, 0, stream>>>(x, wt1, src1, tgt1, sorted1, meta,
                                             basep, pos1, msg);
        edge2_msg<<<grid2, 256, 0, stream>>>(x, wt2, src2, tgt2, sorted2, meta,
                                             basep, pos2, msg);

        // phase 2
        finalize<<<(nn + 3) / 4, 256, 0, stream>>>(x, msg, basep, out, nn);
    } else if (ws_size >= need_r3) {
        int* wsI = (int*)d_ws;
        int* meta = wsI + o_meta;
        int* hist1 = wsI + o_hist1;
        int* off1 = wsI + o_off1;
        int* hist2 = wsI + o_hist2;
        int* off2 = wsI + o_off2;
        int* sorted1 = wsI + o_sorted1;
        int* sorted2 = wsI + o_sorted2;
        unsigned short* wt1 = (unsigned short*)((char*)d_ws + wb_r3);
        unsigned short* wt2 = wt1 + w1_elems;

        copy_kernel<<<2048, 256, 0, stream>>>(out, x, nn * D);
        hipMemsetAsync(sorted1, 0xFF, (size_t)4 * (cap1 + cap2), stream);

        conv_w<<<dim3(4, 4, 4), 256, 0, stream>>>(W1, wt1, D);
        conv_w<<<dim3(8, 4, 4), 256, 0, stream>>>(W2, wt2, 2 * D);

        hist_types<<<NB, 256, 0, stream>>>(type1, E1c, hist1);
        hist_types<<<NB, 256, 0, stream>>>(type2, E2c, hist2);
        scan_offsets<<<1, 64, 0, stream>>>(meta, hist1, off1, hist2, off2);
        write_sorted<<<NB, 256, 0, stream>>>(type1, E1c, off1, sorted1);
        write_sorted<<<NB, 256, 0, stream>>>(type2, E2c, off2, sorted2);

        edge1_mfma<<<grid1, 256, 0, stream>>>(x, wt1, src1, tgt1, sorted1, meta, out);
        edge2_mfma<<<grid2, 256, 0, stream>>>(x, wt2, src2, tgt2, sorted2, meta, out);
    } else {
        copy_kernel<<<2048, 256, 0, stream>>>(out, x, nn * D);
        e1_simple<<<2048, 256, 0, stream>>>(x, W1, src1, tgt1, type1, out, E1c);
        e2_simple<<<2048, 256, 0, stream>>>(x, W2, src2, tgt2, type2, out, E2c);
    }
}